// Round 4
// baseline (584.691 us; speedup 1.0000x reference)
//
#include <hip/hip_runtime.h>

using short8  = __attribute__((ext_vector_type(8))) short;
using ushort8 = __attribute__((ext_vector_type(8))) unsigned short;
using f32x4   = __attribute__((ext_vector_type(4))) float;

constexpr int   N = 8192;
constexpr int   D = 512;
constexpr float INV_T_LOG2E = 2.8853900817779268f;  // (1/0.5) * log2(e)
constexpr int   CGROUPS = 32;                        // 32 col groups of 256

static __device__ __forceinline__ unsigned short f2bf(float x) {
  unsigned u = __float_as_uint(x);
  unsigned r = (u + 0x7fffu + ((u >> 16) & 1u)) >> 16;   // RNE
  return (unsigned short)r;
}

static __device__ __forceinline__ void gld16(const unsigned short* g, unsigned short* l) {
  __builtin_amdgcn_global_load_lds(
      (const __attribute__((address_space(1))) void*)g,
      (__attribute__((address_space(3))) void*)l, 16, 0, 0);
}

// One wave per row; rows [0,N) -> out0, [N,2N) -> out1.
__global__ __launch_bounds__(256) void normalize_kernel(
    const float* __restrict__ in0, const float* __restrict__ in1,
    unsigned short* __restrict__ n0, unsigned short* __restrict__ n1) {
  int gw   = (blockIdx.x * 256 + threadIdx.x) >> 6;
  int lane = threadIdx.x & 63;
  const float* src = (gw < N) ? in0 + (size_t)gw * D : in1 + (size_t)(gw - N) * D;
  unsigned short* dst = (gw < N) ? n0 + (size_t)gw * D : n1 + (size_t)(gw - N) * D;

  const float4* s4 = reinterpret_cast<const float4*>(src) + (size_t)lane * 2;
  float4 v0 = s4[0], v1 = s4[1];
  float ss = v0.x*v0.x + v0.y*v0.y + v0.z*v0.z + v0.w*v0.w
           + v1.x*v1.x + v1.y*v1.y + v1.z*v1.z + v1.w*v1.w;
#pragma unroll
  for (int m = 1; m <= 32; m <<= 1) ss += __shfl_xor(ss, m);
  float scale = 1.0f / fmaxf(sqrtf(ss), 1e-12f);

  ushort8 o;
  o[0] = f2bf(v0.x * scale); o[1] = f2bf(v0.y * scale);
  o[2] = f2bf(v0.z * scale); o[3] = f2bf(v0.w * scale);
  o[4] = f2bf(v1.x * scale); o[5] = f2bf(v1.y * scale);
  o[6] = f2bf(v1.z * scale); o[7] = f2bf(v1.w * scale);
  *(reinterpret_cast<ushort8*>(dst) + lane) = o;
}

// Fused GEMM(bf16 MFMA, 256x256 tile, BK=64, 8 waves) + exp + masked row-sums.
// Phased schedule derived from the m201 template: 4 phases/K-tile,
// raw s_barrier intra-phase, __syncthreads at K-tile boundary (vmcnt collect),
// T2 XOR-swizzled LDS (pre-swizzled global src + swizzled ds_read), T5 setprio.
__global__ __launch_bounds__(512, 2) void ntxent_main(
    const unsigned short* __restrict__ n0, const unsigned short* __restrict__ n1,
    const int* __restrict__ labels,
    float* __restrict__ part_pos, float* __restrict__ part_all) {
  __shared__ unsigned short As[2][256 * 64];   // 64 KiB
  __shared__ unsigned short Bs[2][256 * 64];   // 64 KiB  (total 128 KiB)

  const int t    = threadIdx.x;
  const int lane = t & 63;
  const int wid  = t >> 6;
  const int lr   = lane & 15;
  const int lhi  = lane >> 4;
  const int wr   = wid >> 2;   // 0/1 : rows wr*128..+128
  const int wc   = wid & 3;    // 0..3: cols wc*64..+64

  // Bijective XCD swizzle (grid = 1024, %8==0)
  const int swz = (blockIdx.x & 7) * 128 + (blockIdx.x >> 3);
  const int rowtile = swz >> 5;        // 32 row tiles
  const int colgrp  = swz & 31;        // 32 col groups
  const int rowbase = rowtile * 256;
  const int colbase = colgrp * 256;

  // ---- staging (pre-swizzled global source; linear gld16 dest) ----
  // sweep = 512 thr x 16B = 64 rows x 128B. Thread t -> row srow, 16B slot
  // sslot = (t&7) ^ (srow&7)  (involution; LDS linear slot (t&7) then holds
  // global slot (t&7)^(row&7), matching the swizzled read below).
  const int srow  = t >> 3;                  // 0..63
  const int sslot = (t & 7) ^ (srow & 7);
  const unsigned short* gA = n0 + (size_t)(rowbase + srow) * D + sslot * 8;
  const unsigned short* gB = n1 + (size_t)(colbase + srow) * D + sslot * 8;
  unsigned short* const lA = &As[0][0] + wid * 512;  // wave-uniform base
  unsigned short* const lB = &Bs[0][0] + wid * 512;

  // ---- ds_read offsets (swizzled): elem = row*64 + ((ks*4+lhi)^(row&7))*8 ----
  int aoff[8], asw[8];
#pragma unroll
  for (int m = 0; m < 8; ++m) {
    int row = wr * 128 + m * 16 + lr;
    aoff[m] = row * 64;  asw[m] = row & 7;
  }
  int boff[4], bsw[4];
#pragma unroll
  for (int j = 0; j < 4; ++j) {
    int cr = wc * 64 + j * 16 + lr;
    boff[j] = cr * 64;  bsw[j] = cr & 7;
  }

  f32x4 acc[8][4];
#pragma unroll
  for (int m = 0; m < 8; ++m)
#pragma unroll
    for (int j = 0; j < 4; ++j) acc[m][j] = (f32x4){0.f, 0.f, 0.f, 0.f};

  // prologue: stage kt=0 into buf 0
#pragma unroll
  for (int s = 0; s < 4; ++s) {
    gld16(gA + (size_t)s * 64 * D, lA + s * 4096);
    gld16(gB + (size_t)s * 64 * D, lB + s * 4096);
  }
  __syncthreads();

  for (int kt = 0; kt < 8; ++kt) {
    const int c = kt & 1;
    const unsigned short* bufA = &As[c][0];
    const unsigned short* bufB = &Bs[c][0];
#pragma unroll
    for (int p = 0; p < 4; ++p) {
      const int mh = p >> 1, ks = p & 1;
      short8 a[4], b[4];
#pragma unroll
      for (int i = 0; i < 4; ++i) {
        const int m = mh * 4 + i;
        a[i] = *(const short8*)&bufA[aoff[m] + (((ks * 4 + lhi) ^ asw[m]) << 3)];
        b[i] = *(const short8*)&bufB[boff[i] + (((ks * 4 + lhi) ^ bsw[i]) << 3)];
      }
      if (kt < 7) {           // front-loaded next-tile staging into free buffer
        if (p == 0) {
          const unsigned short* g = gA + (kt + 1) * 64;
          unsigned short* l = lA + (c ^ 1) * 16384;
#pragma unroll
          for (int s = 0; s < 4; ++s) gld16(g + (size_t)s * 64 * D, l + s * 4096);
        } else if (p == 1) {
          const unsigned short* g = gB + (kt + 1) * 64;
          unsigned short* l = lB + (c ^ 1) * 16384;
#pragma unroll
          for (int s = 0; s < 4; ++s) gld16(g + (size_t)s * 64 * D, l + s * 4096);
        }
      }
      __builtin_amdgcn_s_barrier();
      __builtin_amdgcn_s_setprio(1);
#pragma unroll
      for (int i = 0; i < 4; ++i)
#pragma unroll
        for (int j = 0; j < 4; ++j)
          acc[mh * 4 + i][j] =
              __builtin_amdgcn_mfma_f32_16x16x32_bf16(a[i], b[j], acc[mh * 4 + i][j], 0, 0, 0);
      __builtin_amdgcn_s_setprio(0);
      if (p < 3) __builtin_amdgcn_s_barrier();
    }
    __syncthreads();   // vmcnt(0)+lgkmcnt(0) collect: next tile fully landed
  }

  // ---- epilogue: e = exp2(dot * 2*log2e); masked accumulate ----
  int labr[8][4];
#pragma unroll
  for (int m = 0; m < 8; ++m)
#pragma unroll
    for (int r = 0; r < 4; ++r)
      labr[m][r] = labels[rowbase + wr * 128 + m * 16 + lhi * 4 + r];
  int labc[4];
#pragma unroll
  for (int j = 0; j < 4; ++j) labc[j] = labels[colbase + wc * 64 + j * 16 + lr];

  float allrow[8][4] = {};
  float posrow[8][4] = {};
#pragma unroll
  for (int m = 0; m < 8; ++m)
#pragma unroll
    for (int j = 0; j < 4; ++j)
#pragma unroll
      for (int r = 0; r < 4; ++r) {
        float e = exp2f(acc[m][j][r] * INV_T_LOG2E);
        allrow[m][r] += e;
        if (labr[m][r] == labc[j]) posrow[m][r] += e;
      }

  // reduce over the 16 lanes (lr) sharing lhi
#pragma unroll
  for (int msk = 1; msk <= 8; msk <<= 1)
#pragma unroll
    for (int m = 0; m < 8; ++m)
#pragma unroll
      for (int r = 0; r < 4; ++r) {
        allrow[m][r] += __shfl_xor(allrow[m][r], msk);
        posrow[m][r] += __shfl_xor(posrow[m][r], msk);
      }

  // cross-wave reduce over wc (4 waves per wr); red buffers alias As.
  float* redA = (float*)&As[0][0];            // [3][2][128]
  float* redP = redA + 3 * 2 * 128;
  if (wc != 0 && lr == 0) {
#pragma unroll
    for (int m = 0; m < 8; ++m)
#pragma unroll
      for (int r = 0; r < 4; ++r) {
        int idx = m * 16 + lhi * 4 + r;
        redA[((wc - 1) * 2 + wr) * 128 + idx] = allrow[m][r];
        redP[((wc - 1) * 2 + wr) * 128 + idx] = posrow[m][r];
      }
  }
  __syncthreads();
  if (wc == 0 && lr == 0) {
#pragma unroll
    for (int m = 0; m < 8; ++m)
#pragma unroll
      for (int r = 0; r < 4; ++r) {
        int idx = m * 16 + lhi * 4 + r;
        float a = allrow[m][r], pp = posrow[m][r];
#pragma unroll
        for (int w = 0; w < 3; ++w) {
          a  += redA[(w * 2 + wr) * 128 + idx];
          pp += redP[(w * 2 + wr) * 128 + idx];
        }
        int row = rowbase + wr * 128 + idx;
        part_all[colgrp * N + row] = a;
        part_pos[colgrp * N + row] = pp;
      }
  }
}

__global__ __launch_bounds__(256) void final_reduce(
    const float* __restrict__ part_pos, const float* __restrict__ part_all,
    float* __restrict__ out) {
  __shared__ float red[256];
  float s = 0.f;
  for (int i = threadIdx.x; i < N; i += 256) {
    float a = 0.f, p = 0.f;
#pragma unroll
    for (int cs = 0; cs < CGROUPS; ++cs) {
      a += part_all[cs * N + i];
      p += part_pos[cs * N + i];
    }
    s += logf(a) - logf(p);
  }
  red[threadIdx.x] = s;
  __syncthreads();
  for (int off = 128; off > 0; off >>= 1) {
    if (threadIdx.x < off) red[threadIdx.x] += red[threadIdx.x + off];
    __syncthreads();
  }
  if (threadIdx.x == 0) out[0] = red[0] / (float)N;
}

extern "C" void kernel_launch(void* const* d_in, const int* in_sizes, int n_in,
                              void* d_out, int out_size, void* d_ws, size_t ws_size,
                              hipStream_t stream) {
  const float* out0   = (const float*)d_in[0];
  const float* out1   = (const float*)d_in[1];
  const int*   labels = (const int*)d_in[2];
  float*       out    = (float*)d_out;

  char* ws = (char*)d_ws;
  unsigned short* n0 = (unsigned short*)ws;                          // 8 MB
  unsigned short* n1 = (unsigned short*)(ws + (size_t)N * D * 2);    // 8 MB
  float* part_pos = (float*)(ws + (size_t)2 * N * D * 2);            // 1 MB
  float* part_all = part_pos + (size_t)CGROUPS * N;                  // 1 MB

  hipLaunchKernelGGL(normalize_kernel, dim3(2 * N / 4), dim3(256), 0, stream,
                     out0, out1, n0, n1);
  hipLaunchKernelGGL(ntxent_main, dim3(32 * CGROUPS), dim3(512), 0, stream,
                     n0, n1, labels, part_pos, part_all);
  hipLaunchKernelGGL(final_reduce, dim3(1), dim3(256), 0, stream,
                     part_pos, part_all, out);
}

// Round 5
// 121.516 us; speedup vs baseline: 4.8116x; 4.8116x over previous
//
#include <hip/hip_runtime.h>

using short8  = __attribute__((ext_vector_type(8))) short;
using ushort8 = __attribute__((ext_vector_type(8))) unsigned short;
using f32x4   = __attribute__((ext_vector_type(4))) float;

constexpr int   N = 8192;
constexpr int   D = 512;
constexpr float INV_T_LOG2E = 2.8853900817779268f;  // (1/0.5) * log2(e)
constexpr int   CGROUPS = 32;                        // 32 col groups of 256

static __device__ __forceinline__ unsigned short f2bf(float x) {
  unsigned u = __float_as_uint(x);
  unsigned r = (u + 0x7fffu + ((u >> 16) & 1u)) >> 16;   // RNE
  return (unsigned short)r;
}

static __device__ __forceinline__ void gld16(const unsigned short* g, unsigned short* l) {
  __builtin_amdgcn_global_load_lds(
      (const __attribute__((address_space(1))) void*)g,
      (__attribute__((address_space(3))) void*)l, 16, 0, 0);
}

// One wave per row; rows [0,N) -> out0, [N,2N) -> out1.
__global__ __launch_bounds__(256) void normalize_kernel(
    const float* __restrict__ in0, const float* __restrict__ in1,
    unsigned short* __restrict__ n0, unsigned short* __restrict__ n1) {
  int gw   = (blockIdx.x * 256 + threadIdx.x) >> 6;
  int lane = threadIdx.x & 63;
  const float* src = (gw < N) ? in0 + (size_t)gw * D : in1 + (size_t)(gw - N) * D;
  unsigned short* dst = (gw < N) ? n0 + (size_t)gw * D : n1 + (size_t)(gw - N) * D;

  const float4* s4 = reinterpret_cast<const float4*>(src) + (size_t)lane * 2;
  float4 v0 = s4[0], v1 = s4[1];
  float ss = v0.x*v0.x + v0.y*v0.y + v0.z*v0.z + v0.w*v0.w
           + v1.x*v1.x + v1.y*v1.y + v1.z*v1.z + v1.w*v1.w;
#pragma unroll
  for (int m = 1; m <= 32; m <<= 1) ss += __shfl_xor(ss, m);
  float scale = 1.0f / fmaxf(sqrtf(ss), 1e-12f);

  ushort8 o;
  o[0] = f2bf(v0.x * scale); o[1] = f2bf(v0.y * scale);
  o[2] = f2bf(v0.z * scale); o[3] = f2bf(v0.w * scale);
  o[4] = f2bf(v1.x * scale); o[5] = f2bf(v1.y * scale);
  o[6] = f2bf(v1.z * scale); o[7] = f2bf(v1.w * scale);
  *(reinterpret_cast<ushort8*>(dst) + lane) = o;
}

// Fused GEMM(bf16 MFMA, 256x256 tile, BK=64, 8 waves) + exp + masked row-sums.
// Phased schedule (m201-derived): 4 phases/K-tile, raw s_barrier intra-phase,
// __syncthreads at K-tile boundary; T2 XOR-swizzle; T5 setprio.
__global__ __launch_bounds__(512, 2) void ntxent_main(
    const unsigned short* __restrict__ n0, const unsigned short* __restrict__ n1,
    const int* __restrict__ labels,
    float* __restrict__ part_pos, float* __restrict__ part_all) {
  __shared__ unsigned short As[2][256 * 64];   // 64 KiB
  __shared__ unsigned short Bs[2][256 * 64];   // 64 KiB  (total 128 KiB)

  const int t    = threadIdx.x;
  const int lane = t & 63;
  const int wid  = t >> 6;
  const int lr   = lane & 15;
  const int lhi  = lane >> 4;
  const int wr   = wid >> 2;   // 0/1 : rows wr*128..+128
  const int wc   = wid & 3;    // 0..3: cols wc*64..+64

  // Bijective XCD swizzle (grid = 1024, %8==0)
  const int swz = (blockIdx.x & 7) * 128 + (blockIdx.x >> 3);
  const int rowtile = swz >> 5;        // 32 row tiles
  const int colgrp  = swz & 31;        // 32 col groups
  const int rowbase = rowtile * 256;
  const int colbase = colgrp * 256;

  // ---- staging (pre-swizzled global source; linear gld16 dest) ----
  const int srow  = t >> 3;                  // 0..63
  const int sslot = (t & 7) ^ (srow & 7);
  const unsigned short* gA = n0 + (size_t)(rowbase + srow) * D + sslot * 8;
  const unsigned short* gB = n1 + (size_t)(colbase + srow) * D + sslot * 8;
  unsigned short* const lA = &As[0][0] + wid * 512;  // wave-uniform base
  unsigned short* const lB = &Bs[0][0] + wid * 512;

  // ---- ds_read offsets (swizzled) ----
  int aoff[8], asw[8];
#pragma unroll
  for (int m = 0; m < 8; ++m) {
    int row = wr * 128 + m * 16 + lr;
    aoff[m] = row * 64;  asw[m] = row & 7;
  }
  int boff[4], bsw[4];
#pragma unroll
  for (int j = 0; j < 4; ++j) {
    int cr = wc * 64 + j * 16 + lr;
    boff[j] = cr * 64;  bsw[j] = cr & 7;
  }

  f32x4 acc[8][4];
#pragma unroll
  for (int m = 0; m < 8; ++m)
#pragma unroll
    for (int j = 0; j < 4; ++j) acc[m][j] = (f32x4){0.f, 0.f, 0.f, 0.f};

  // prologue: stage kt=0 into buf 0
#pragma unroll
  for (int s = 0; s < 4; ++s) {
    gld16(gA + (size_t)s * 64 * D, lA + s * 4096);
    gld16(gB + (size_t)s * 64 * D, lB + s * 4096);
  }
  __syncthreads();

  for (int kt = 0; kt < 8; ++kt) {
    const int c = kt & 1;
    const unsigned short* bufA = &As[c][0];
    const unsigned short* bufB = &Bs[c][0];
#pragma unroll
    for (int p = 0; p < 4; ++p) {
      const int mh = p >> 1, ks = p & 1;
      short8 a[4], b[4];
#pragma unroll
      for (int i = 0; i < 4; ++i) {
        const int m = mh * 4 + i;
        a[i] = *(const short8*)&bufA[aoff[m] + (((ks * 4 + lhi) ^ asw[m]) << 3)];
        b[i] = *(const short8*)&bufB[boff[i] + (((ks * 4 + lhi) ^ bsw[i]) << 3)];
      }
      if (kt < 7) {           // front-loaded next-tile staging into free buffer
        if (p == 0) {
          const unsigned short* g = gA + (kt + 1) * 64;
          unsigned short* l = lA + (c ^ 1) * 16384;
#pragma unroll
          for (int s = 0; s < 4; ++s) gld16(g + (size_t)s * 64 * D, l + s * 4096);
        } else if (p == 1) {
          const unsigned short* g = gB + (kt + 1) * 64;
          unsigned short* l = lB + (c ^ 1) * 16384;
#pragma unroll
          for (int s = 0; s < 4; ++s) gld16(g + (size_t)s * 64 * D, l + s * 4096);
        }
      }
      __builtin_amdgcn_s_barrier();
      __builtin_amdgcn_s_setprio(1);
#pragma unroll
      for (int i = 0; i < 4; ++i)
#pragma unroll
        for (int j = 0; j < 4; ++j)
          acc[mh * 4 + i][j] =
              __builtin_amdgcn_mfma_f32_16x16x32_bf16(a[i], b[j], acc[mh * 4 + i][j], 0, 0, 0);
      __builtin_amdgcn_s_setprio(0);
      if (p < 3) __builtin_amdgcn_s_barrier();
    }
    __syncthreads();   // vmcnt(0)+lgkmcnt(0) collect: next tile fully landed
  }

  // ---- epilogue: e = exp2(dot * 2*log2e); masked accumulate ----
  int labr[8][4];
#pragma unroll
  for (int m = 0; m < 8; ++m)
#pragma unroll
    for (int r = 0; r < 4; ++r)
      labr[m][r] = labels[rowbase + wr * 128 + m * 16 + lhi * 4 + r];
  int labc[4];
#pragma unroll
  for (int j = 0; j < 4; ++j) labc[j] = labels[colbase + wc * 64 + j * 16 + lr];

  float allrow[8][4] = {};
  float posrow[8][4] = {};
#pragma unroll
  for (int m = 0; m < 8; ++m)
#pragma unroll
    for (int j = 0; j < 4; ++j)
#pragma unroll
      for (int r = 0; r < 4; ++r) {
        float e = exp2f(acc[m][j][r] * INV_T_LOG2E);
        allrow[m][r] += e;
        if (labr[m][r] == labc[j]) posrow[m][r] += e;
      }

  // reduce over the 16 lanes (lr) sharing lhi
#pragma unroll
  for (int msk = 1; msk <= 8; msk <<= 1)
#pragma unroll
    for (int m = 0; m < 8; ++m)
#pragma unroll
      for (int r = 0; r < 4; ++r) {
        allrow[m][r] += __shfl_xor(allrow[m][r], msk);
        posrow[m][r] += __shfl_xor(posrow[m][r], msk);
      }

  // cross-wave reduce over wc (4 waves per wr); red buffers alias As.
  float* redA = (float*)&As[0][0];            // [3][2][128]
  float* redP = redA + 3 * 2 * 128;
  if (wc != 0 && lr == 0) {
#pragma unroll
    for (int m = 0; m < 8; ++m)
#pragma unroll
      for (int r = 0; r < 4; ++r) {
        int idx = m * 16 + lhi * 4 + r;
        redA[((wc - 1) * 2 + wr) * 128 + idx] = allrow[m][r];
        redP[((wc - 1) * 2 + wr) * 128 + idx] = posrow[m][r];
      }
  }
  __syncthreads();
  if (wc == 0 && lr == 0) {
#pragma unroll
    for (int m = 0; m < 8; ++m)
#pragma unroll
      for (int r = 0; r < 4; ++r) {
        int idx = m * 16 + lhi * 4 + r;
        float a = allrow[m][r], pp = posrow[m][r];
#pragma unroll
        for (int w = 0; w < 3; ++w) {
          a  += redA[(w * 2 + wr) * 128 + idx];
          pp += redP[(w * 2 + wr) * 128 + idx];
        }
        int row = rowbase + wr * 128 + idx;
        part_all[colgrp * N + row] = a;
        part_pos[colgrp * N + row] = pp;
      }
  }
}

// Stage 1: one row per thread, coalesced over cs; per-block tree reduce.
__global__ __launch_bounds__(256) void row_reduce(
    const float* __restrict__ part_pos, const float* __restrict__ part_all,
    float* __restrict__ blocksum) {
  const int i = blockIdx.x * 256 + threadIdx.x;   // row
  float a = 0.f, p = 0.f;
#pragma unroll 4
  for (int cs = 0; cs < CGROUPS; ++cs) {
    a += part_all[(size_t)cs * N + i];
    p += part_pos[(size_t)cs * N + i];
  }
  float s = logf(a) - logf(p);
  __shared__ float red[256];
  red[threadIdx.x] = s;
  __syncthreads();
  for (int off = 128; off > 0; off >>= 1) {
    if (threadIdx.x < off) red[threadIdx.x] += red[threadIdx.x + off];
    __syncthreads();
  }
  if (threadIdx.x == 0) blocksum[blockIdx.x] = red[0];
}

// Stage 2: one wave sums the 32 block partials.
__global__ __launch_bounds__(64) void final_sum(
    const float* __restrict__ blocksum, float* __restrict__ out) {
  float s = (threadIdx.x < N / 256) ? blocksum[threadIdx.x] : 0.f;
#pragma unroll
  for (int m = 1; m <= 32; m <<= 1) s += __shfl_xor(s, m);
  if (threadIdx.x == 0) out[0] = s / (float)N;
}

extern "C" void kernel_launch(void* const* d_in, const int* in_sizes, int n_in,
                              void* d_out, int out_size, void* d_ws, size_t ws_size,
                              hipStream_t stream) {
  const float* out0   = (const float*)d_in[0];
  const float* out1   = (const float*)d_in[1];
  const int*   labels = (const int*)d_in[2];
  float*       out    = (float*)d_out;

  char* ws = (char*)d_ws;
  unsigned short* n0 = (unsigned short*)ws;                          // 8 MB
  unsigned short* n1 = (unsigned short*)(ws + (size_t)N * D * 2);    // 8 MB
  float* part_pos = (float*)(ws + (size_t)2 * N * D * 2);            // 1 MB
  float* part_all = part_pos + (size_t)CGROUPS * N;                  // 1 MB
  float* blocksum = part_all + (size_t)CGROUPS * N;                  // 128 B

  hipLaunchKernelGGL(normalize_kernel, dim3(2 * N / 4), dim3(256), 0, stream,
                     out0, out1, n0, n1);
  hipLaunchKernelGGL(ntxent_main, dim3(32 * CGROUPS), dim3(512), 0, stream,
                     n0, n1, labels, part_pos, part_all);
  hipLaunchKernelGGL(row_reduce, dim3(N / 256), dim3(256), 0, stream,
                     part_pos, part_all, blocksum);
  hipLaunchKernelGGL(final_sum, dim3(1), dim3(64), 0, stream,
                     blocksum, out);
}

// Round 6
// 119.275 us; speedup vs baseline: 4.9020x; 1.0188x over previous
//
#include <hip/hip_runtime.h>

using short8  = __attribute__((ext_vector_type(8))) short;
using ushort8 = __attribute__((ext_vector_type(8))) unsigned short;
using f32x4   = __attribute__((ext_vector_type(4))) float;

constexpr int   N = 8192;
constexpr int   D = 512;
constexpr float INV_T_LOG2E = 2.8853900817779268f;  // (1/0.5) * log2(e)
constexpr int   CGROUPS = 32;                        // 32 col groups of 256
constexpr int   BK = 32;
constexpr int   NKT = D / BK;                        // 16 K-tiles

static __device__ __forceinline__ unsigned short f2bf(float x) {
  unsigned u = __float_as_uint(x);
  unsigned r = (u + 0x7fffu + ((u >> 16) & 1u)) >> 16;   // RNE
  return (unsigned short)r;
}

static __device__ __forceinline__ void gld16(const unsigned short* g, unsigned short* l) {
  __builtin_amdgcn_global_load_lds(
      (const __attribute__((address_space(1))) void*)g,
      (__attribute__((address_space(3))) void*)l, 16, 0, 0);
}

// One wave per row; rows [0,N) -> out0, [N,2N) -> out1.
__global__ __launch_bounds__(256) void normalize_kernel(
    const float* __restrict__ in0, const float* __restrict__ in1,
    unsigned short* __restrict__ n0, unsigned short* __restrict__ n1) {
  int gw   = (blockIdx.x * 256 + threadIdx.x) >> 6;
  int lane = threadIdx.x & 63;
  const float* src = (gw < N) ? in0 + (size_t)gw * D : in1 + (size_t)(gw - N) * D;
  unsigned short* dst = (gw < N) ? n0 + (size_t)gw * D : n1 + (size_t)(gw - N) * D;

  const float4* s4 = reinterpret_cast<const float4*>(src) + (size_t)lane * 2;
  float4 v0 = s4[0], v1 = s4[1];
  float ss = v0.x*v0.x + v0.y*v0.y + v0.z*v0.z + v0.w*v0.w
           + v1.x*v1.x + v1.y*v1.y + v1.z*v1.z + v1.w*v1.w;
#pragma unroll
  for (int m = 1; m <= 32; m <<= 1) ss += __shfl_xor(ss, m);
  float scale = 1.0f / fmaxf(sqrtf(ss), 1e-12f);

  ushort8 o;
  o[0] = f2bf(v0.x * scale); o[1] = f2bf(v0.y * scale);
  o[2] = f2bf(v0.z * scale); o[3] = f2bf(v0.w * scale);
  o[4] = f2bf(v1.x * scale); o[5] = f2bf(v1.y * scale);
  o[6] = f2bf(v1.z * scale); o[7] = f2bf(v1.w * scale);
  *(reinterpret_cast<ushort8*>(dst) + lane) = o;
}

// Fused GEMM(bf16 MFMA, 256x256 tile, BK=32, 8 waves) + exp + masked row-sums.
// 4-deep circular LDS pipeline, counted vmcnt (T3/T4), T2 swizzle, T5 setprio.
__global__ __launch_bounds__(512, 2) void ntxent_main(
    const unsigned short* __restrict__ n0, const unsigned short* __restrict__ n1,
    const int* __restrict__ labels,
    float* __restrict__ part_pos, float* __restrict__ part_all) {
  __shared__ unsigned short As[4][256 * BK];   // 4 x 16 KiB
  __shared__ unsigned short Bs[4][256 * BK];   // 4 x 16 KiB  (total 128 KiB)

  const int t    = threadIdx.x;
  const int lane = t & 63;
  const int wid  = t >> 6;
  const int lr   = lane & 15;
  const int lhi  = lane >> 4;
  const int wr   = wid >> 2;   // 0/1 : rows wr*128..+128
  const int wc   = wid & 3;    // 0..3: cols wc*64..+64

  // Bijective XCD swizzle (grid = 1024, %8==0)
  const int swz = (blockIdx.x & 7) * 128 + (blockIdx.x >> 3);
  const int rowtile = swz >> 5;        // 32 row tiles
  const int colgrp  = swz & 31;        // 32 col groups
  const int rowbase = rowtile * 256;
  const int colbase = colgrp * 256;

  // ---- staging (pre-swizzled global source; linear gld16 dest) ----
  // tile = [256 rows][4 slots of 16B]; physical slot = slot ^ ((row>>1)&3).
  // sweep s covers rows s*128..s*128+127: thread t -> row s*128+(t>>2), phys slot t&3,
  // so global (logical) slot = (t&3) ^ ((row>>1)&3) = (t&3) ^ ((t>>3)&3).
  const int gslot = (t & 3) ^ ((t >> 3) & 3);
  const unsigned short* gA = n0 + (size_t)(rowbase + (t >> 2)) * D + gslot * 8;
  const unsigned short* gB = n1 + (size_t)(colbase + (t >> 2)) * D + gslot * 8;
  unsigned short* const lA = &As[0][0] + wid * 512;  // + buf*8192 + s*4096
  unsigned short* const lB = &Bs[0][0] + wid * 512;

  // ---- ds_read indices (swizzled): elem ofs = row*32 + (lhi^((lr>>1)&3))*8 ----
  const int ksl = lhi ^ ((lr >> 1) & 3);
  int aidx[8];
#pragma unroll
  for (int m = 0; m < 8; ++m) aidx[m] = (wr * 128 + m * 16 + lr) * BK + ksl * 8;
  int bidx[4];
#pragma unroll
  for (int j = 0; j < 4; ++j) bidx[j] = (wc * 64 + j * 16 + lr) * BK + ksl * 8;

  f32x4 acc[8][4];
#pragma unroll
  for (int m = 0; m < 8; ++m)
#pragma unroll
    for (int j = 0; j < 4; ++j) acc[m][j] = (f32x4){0.f, 0.f, 0.f, 0.f};

  // prologue: stage tiles 0,1,2 (grouped per tile for vmcnt accounting)
#pragma unroll
  for (int pt = 0; pt < 3; ++pt) {
#pragma unroll
    for (int s = 0; s < 2; ++s)
      gld16(gA + (size_t)s * 128 * D + pt * BK, lA + pt * 8192 + s * 4096);
#pragma unroll
    for (int s = 0; s < 2; ++s)
      gld16(gB + (size_t)s * 128 * D + pt * BK, lB + pt * 8192 + s * 4096);
  }

#pragma unroll
  for (int kt = 0; kt < NKT; ++kt) {
    // Wait own oldest tile's loads, then publish via barrier (fused: nothing
    // may cross). Outstanding at top: tiles kt,kt+1,kt+2 (4 loads each).
    if (kt <= NKT - 3)
      asm volatile("s_waitcnt vmcnt(8)\n\ts_barrier" ::: "memory");
    else if (kt == NKT - 2)
      asm volatile("s_waitcnt vmcnt(4)\n\ts_barrier" ::: "memory");
    else
      asm volatile("s_waitcnt vmcnt(0)\n\ts_barrier" ::: "memory");

    if (kt <= NKT - 4) {   // stage tile kt+3 into buf (kt+3)&3 (readers done)
      const int st = kt + 3, sb = st & 3;
#pragma unroll
      for (int s = 0; s < 2; ++s)
        gld16(gA + (size_t)s * 128 * D + st * BK, lA + sb * 8192 + s * 4096);
#pragma unroll
      for (int s = 0; s < 2; ++s)
        gld16(gB + (size_t)s * 128 * D + st * BK, lB + sb * 8192 + s * 4096);
    }

    const unsigned short* bufA = &As[kt & 3][0];
    const unsigned short* bufB = &Bs[kt & 3][0];
    short8 a[8], b[4];
#pragma unroll
    for (int m = 0; m < 8; ++m) a[m] = *(const short8*)&bufA[aidx[m]];
#pragma unroll
    for (int j = 0; j < 4; ++j) b[j] = *(const short8*)&bufB[bidx[j]];

    __builtin_amdgcn_s_setprio(1);
#pragma unroll
    for (int m = 0; m < 8; ++m)
#pragma unroll
      for (int j = 0; j < 4; ++j)
        acc[m][j] = __builtin_amdgcn_mfma_f32_16x16x32_bf16(a[m], b[j], acc[m][j], 0, 0, 0);
    __builtin_amdgcn_s_setprio(0);
  }

  // ---- epilogue: e = exp2(dot * 2*log2e); masked accumulate ----
  int labr[8][4];
#pragma unroll
  for (int m = 0; m < 8; ++m)
#pragma unroll
    for (int r = 0; r < 4; ++r)
      labr[m][r] = labels[rowbase + wr * 128 + m * 16 + lhi * 4 + r];
  int labc[4];
#pragma unroll
  for (int j = 0; j < 4; ++j) labc[j] = labels[colbase + wc * 64 + j * 16 + lr];

  float allrow[8][4] = {};
  float posrow[8][4] = {};
#pragma unroll
  for (int m = 0; m < 8; ++m)
#pragma unroll
    for (int j = 0; j < 4; ++j)
#pragma unroll
      for (int r = 0; r < 4; ++r) {
        float e = exp2f(acc[m][j][r] * INV_T_LOG2E);
        allrow[m][r] += e;
        if (labr[m][r] == labc[j]) posrow[m][r] += e;
      }

  // reduce over the 16 lanes (lr) sharing lhi
#pragma unroll
  for (int msk = 1; msk <= 8; msk <<= 1)
#pragma unroll
    for (int m = 0; m < 8; ++m)
#pragma unroll
      for (int r = 0; r < 4; ++r) {
        allrow[m][r] += __shfl_xor(allrow[m][r], msk);
        posrow[m][r] += __shfl_xor(posrow[m][r], msk);
      }

  // cross-wave reduce over wc (4 waves per wr); red buffers alias As buf0
  // (quiescent: last read was tile 12, >=3 barriers ago; all DMA landed).
  float* redA = (float*)&As[0][0];            // [3][2][128]
  float* redP = redA + 3 * 2 * 128;
  if (wc != 0 && lr == 0) {
#pragma unroll
    for (int m = 0; m < 8; ++m)
#pragma unroll
      for (int r = 0; r < 4; ++r) {
        int idx = m * 16 + lhi * 4 + r;
        redA[((wc - 1) * 2 + wr) * 128 + idx] = allrow[m][r];
        redP[((wc - 1) * 2 + wr) * 128 + idx] = posrow[m][r];
      }
  }
  __syncthreads();
  if (wc == 0 && lr == 0) {
#pragma unroll
    for (int m = 0; m < 8; ++m)
#pragma unroll
      for (int r = 0; r < 4; ++r) {
        int idx = m * 16 + lhi * 4 + r;
        float a = allrow[m][r], pp = posrow[m][r];
#pragma unroll
        for (int w = 0; w < 3; ++w) {
          a  += redA[(w * 2 + wr) * 128 + idx];
          pp += redP[(w * 2 + wr) * 128 + idx];
        }
        int row = rowbase + wr * 128 + idx;
        part_all[colgrp * N + row] = a;
        part_pos[colgrp * N + row] = pp;
      }
  }
}

// Stage 1: one row per thread, coalesced over cs; per-block tree reduce.
__global__ __launch_bounds__(256) void row_reduce(
    const float* __restrict__ part_pos, const float* __restrict__ part_all,
    float* __restrict__ blocksum) {
  const int i = blockIdx.x * 256 + threadIdx.x;   // row
  float a = 0.f, p = 0.f;
#pragma unroll 4
  for (int cs = 0; cs < CGROUPS; ++cs) {
    a += part_all[(size_t)cs * N + i];
    p += part_pos[(size_t)cs * N + i];
  }
  float s = logf(a) - logf(p);
  __shared__ float red[256];
  red[threadIdx.x] = s;
  __syncthreads();
  for (int off = 128; off > 0; off >>= 1) {
    if (threadIdx.x < off) red[threadIdx.x] += red[threadIdx.x + off];
    __syncthreads();
  }
  if (threadIdx.x == 0) blocksum[blockIdx.x] = red[0];
}

// Stage 2: one wave sums the 32 block partials.
__global__ __launch_bounds__(64) void final_sum(
    const float* __restrict__ blocksum, float* __restrict__ out) {
  float s = (threadIdx.x < N / 256) ? blocksum[threadIdx.x] : 0.f;
#pragma unroll
  for (int m = 1; m <= 32; m <<= 1) s += __shfl_xor(s, m);
  if (threadIdx.x == 0) out[0] = s / (float)N;
}

extern "C" void kernel_launch(void* const* d_in, const int* in_sizes, int n_in,
                              void* d_out, int out_size, void* d_ws, size_t ws_size,
                              hipStream_t stream) {
  const float* out0   = (const float*)d_in[0];
  const float* out1   = (const float*)d_in[1];
  const int*   labels = (const int*)d_in[2];
  float*       out    = (float*)d_out;

  char* ws = (char*)d_ws;
  unsigned short* n0 = (unsigned short*)ws;                          // 8 MB
  unsigned short* n1 = (unsigned short*)(ws + (size_t)N * D * 2);    // 8 MB
  float* part_pos = (float*)(ws + (size_t)2 * N * D * 2);            // 1 MB
  float* part_all = part_pos + (size_t)CGROUPS * N;                  // 1 MB
  float* blocksum = part_all + (size_t)CGROUPS * N;                  // 128 B

  hipLaunchKernelGGL(normalize_kernel, dim3(2 * N / 4), dim3(256), 0, stream,
                     out0, out1, n0, n1);
  hipLaunchKernelGGL(ntxent_main, dim3(32 * CGROUPS), dim3(512), 0, stream,
                     n0, n1, labels, part_pos, part_all);
  hipLaunchKernelGGL(row_reduce, dim3(N / 256), dim3(256), 0, stream,
                     part_pos, part_all, blocksum);
  hipLaunchKernelGGL(final_sum, dim3(1), dim3(64), 0, stream,
                     blocksum, out);
}

// Round 7
// 118.008 us; speedup vs baseline: 4.9547x; 1.0107x over previous
//
#include <hip/hip_runtime.h>

using short8  = __attribute__((ext_vector_type(8))) short;
using ushort8 = __attribute__((ext_vector_type(8))) unsigned short;
using f32x4   = __attribute__((ext_vector_type(4))) float;

constexpr int   N = 8192;
constexpr int   D = 512;
constexpr float INV_T_LOG2E = 2.8853900817779268f;  // (1/0.5) * log2(e)
constexpr int   CGROUPS = 32;                        // 32 col groups of 256

static __device__ __forceinline__ unsigned short f2bf(float x) {
  unsigned u = __float_as_uint(x);
  unsigned r = (u + 0x7fffu + ((u >> 16) & 1u)) >> 16;   // RNE
  return (unsigned short)r;
}

static __device__ __forceinline__ void gld16(const unsigned short* g, unsigned short* l) {
  __builtin_amdgcn_global_load_lds(
      (const __attribute__((address_space(1))) void*)g,
      (__attribute__((address_space(3))) void*)l, 16, 0, 0);
}

// One wave per row; rows [0,N) -> out0, [N,2N) -> out1.
__global__ __launch_bounds__(256) void normalize_kernel(
    const float* __restrict__ in0, const float* __restrict__ in1,
    unsigned short* __restrict__ n0, unsigned short* __restrict__ n1) {
  int gw   = (blockIdx.x * 256 + threadIdx.x) >> 6;
  int lane = threadIdx.x & 63;
  const float* src = (gw < N) ? in0 + (size_t)gw * D : in1 + (size_t)(gw - N) * D;
  unsigned short* dst = (gw < N) ? n0 + (size_t)gw * D : n1 + (size_t)(gw - N) * D;

  const float4* s4 = reinterpret_cast<const float4*>(src) + (size_t)lane * 2;
  float4 v0 = s4[0], v1 = s4[1];
  float ss = v0.x*v0.x + v0.y*v0.y + v0.z*v0.z + v0.w*v0.w
           + v1.x*v1.x + v1.y*v1.y + v1.z*v1.z + v1.w*v1.w;
#pragma unroll
  for (int m = 1; m <= 32; m <<= 1) ss += __shfl_xor(ss, m);
  float scale = 1.0f / fmaxf(sqrtf(ss), 1e-12f);

  ushort8 o;
  o[0] = f2bf(v0.x * scale); o[1] = f2bf(v0.y * scale);
  o[2] = f2bf(v0.z * scale); o[3] = f2bf(v0.w * scale);
  o[4] = f2bf(v1.x * scale); o[5] = f2bf(v1.y * scale);
  o[6] = f2bf(v1.z * scale); o[7] = f2bf(v1.w * scale);
  *(reinterpret_cast<ushort8*>(dst) + lane) = o;
}

// Fused GEMM(bf16 MFMA, 256x256 tile, 8 waves) + exp + masked row-sums.
// 8-phase schedule (T3+T4): 2 K-tiles (BK=64) per iteration, per phase
// {ds_read quadrant, stage one 16KB region, barrier, setprio+16 MFMA, barrier};
// vmcnt(4) gates fused into end-barriers of phases 4 and 8 only.
__global__ __launch_bounds__(512, 2) void ntxent_main(
    const unsigned short* __restrict__ n0, const unsigned short* __restrict__ n1,
    const int* __restrict__ labels,
    float* __restrict__ part_pos, float* __restrict__ part_all) {
  __shared__ unsigned short As[2][256 * 64];   // dbuf0 = even K-tiles, dbuf1 = odd
  __shared__ unsigned short Bs[2][256 * 64];   // total 128 KiB

  const int t    = threadIdx.x;
  const int lane = t & 63;
  const int wid  = t >> 6;
  const int lr   = lane & 15;
  const int lhi  = lane >> 4;
  const int wr   = wid >> 2;   // 0/1 : rows wr*128..+128
  const int wc   = wid & 3;    // 0..3: cols wc*64..+64

  // Bijective XCD swizzle (grid = 1024, %8==0)
  const int swz = (blockIdx.x & 7) * 128 + (blockIdx.x >> 3);
  const int rowtile = swz >> 5;
  const int colgrp  = swz & 31;
  const int rowbase = rowtile * 256;
  const int colbase = colgrp * 256;

  // ---- staging precompute (pre-swizzled global source; linear gld16 dest) ----
  const int srow  = t >> 3;                       // 0..63
  const int gslot = (t & 7) ^ (srow & 7);
  const unsigned short* gA0 = n0 + (size_t)(rowbase + srow) * D + gslot * 8;
  const unsigned short* gB0 = n1 + (size_t)colbase * D + gslot * 8;
  const int rb0 = (srow >> 5) * 64 + (srow & 31); // B stripe-row base
  unsigned short* const lA0 = &As[0][0] + srow * 64 + (t & 7) * 8;
  unsigned short* const lB0 = &Bs[0][0] + (t & 7) * 8;

  // A region (quadset qs): rows {qs*64..+64} u {128+qs*64..+64} of the tile
#define STAGE_A(tile, qs) do { \
    unsigned short* _d = lA0 + ((tile) & 1) * 16384 + (qs) * 64 * 64; \
    const unsigned short* _g = gA0 + (size_t)((qs) * 64) * D + (tile) * 64; \
    gld16(_g, _d); \
    gld16(_g + (size_t)128 * D, _d + 128 * 64); \
  } while (0)
  // B region (quadset qs): 32-row stripes {qs*32 + k*64}
#define STAGE_B(tile, qs) do { \
    unsigned short* _d = lB0 + ((tile) & 1) * 16384 + (rb0 + (qs) * 32) * 64; \
    const unsigned short* _g = gB0 + (size_t)(rb0 + (qs) * 32) * D + (tile) * 64; \
    gld16(_g, _d); \
    gld16(_g + (size_t)128 * D, _d + 128 * 64); \
  } while (0)

  // ---- ds_read offsets (T2 swizzle; measured 0-conflict layout) ----
  const int sw8 = lr & 7;
  const int ko0 = ((lhi) ^ sw8) << 3;
  const int ko1 = ((4 + lhi) ^ sw8) << 3;
  int aoff[8];
#pragma unroll
  for (int m = 0; m < 8; ++m) aoff[m] = (wr * 128 + m * 16 + lr) * 64;
  int boff[4];
#pragma unroll
  for (int j = 0; j < 4; ++j) boff[j] = (wc * 64 + j * 16 + lr) * 64;

#define LDA_Q(buf, mh) do { \
    _Pragma("unroll") for (int q = 0; q < 4; ++q) { \
      aq[q * 2 + 0] = *(const short8*)&(buf)[aoff[(mh) * 4 + q] + ko0]; \
      aq[q * 2 + 1] = *(const short8*)&(buf)[aoff[(mh) * 4 + q] + ko1]; \
    } \
  } while (0)
#define LDB_Q(buf, dst, jh) do { \
    _Pragma("unroll") for (int jj = 0; jj < 2; ++jj) { \
      dst[jj * 2 + 0] = *(const short8*)&(buf)[boff[(jh) * 2 + jj] + ko0]; \
      dst[jj * 2 + 1] = *(const short8*)&(buf)[boff[(jh) * 2 + jj] + ko1]; \
    } \
  } while (0)
#define MFMA_Q(mh, jh, bq) do { \
    _Pragma("unroll") for (int q = 0; q < 4; ++q) \
      _Pragma("unroll") for (int jj = 0; jj < 2; ++jj) { \
        acc[(mh) * 4 + q][(jh) * 2 + jj] = __builtin_amdgcn_mfma_f32_16x16x32_bf16( \
            aq[q * 2 + 0], bq[jj * 2 + 0], acc[(mh) * 4 + q][(jh) * 2 + jj], 0, 0, 0); \
        acc[(mh) * 4 + q][(jh) * 2 + jj] = __builtin_amdgcn_mfma_f32_16x16x32_bf16( \
            aq[q * 2 + 1], bq[jj * 2 + 1], acc[(mh) * 4 + q][(jh) * 2 + jj], 0, 0, 0); \
      } \
  } while (0)

#define BAR   asm volatile("s_barrier" ::: "memory")
#define GATE4 asm volatile("s_waitcnt vmcnt(4)\n\ts_barrier" ::: "memory")
#define GATE0 asm volatile("s_waitcnt vmcnt(0)\n\ts_barrier" ::: "memory")
#define PRIO1 __builtin_amdgcn_s_setprio(1)
#define PRIO0 __builtin_amdgcn_s_setprio(0)

  f32x4 acc[8][4];
#pragma unroll
  for (int m = 0; m < 8; ++m)
#pragma unroll
    for (int j = 0; j < 4; ++j) acc[m][j] = (f32x4){0.f, 0.f, 0.f, 0.f};

  short8 aq[8], b0[4], b1[4];

  // prologue: stage t0 fully + t1 {A-qs0, B-qs1}; drain t0, keep t1 in flight.
  STAGE_A(0, 0); STAGE_B(0, 1); STAGE_A(0, 1); STAGE_B(0, 0);
  STAGE_A(1, 0); STAGE_B(1, 1);
  GATE4;

  const unsigned short* const A0b = &As[0][0];
  const unsigned short* const B0b = &Bs[0][0];
  const unsigned short* const A1b = &As[1][0];
  const unsigned short* const B1b = &Bs[1][0];

#pragma unroll
  for (int it = 0; it < 4; ++it) {
    const int e = 2 * it, o = e + 1;
    // p0 (mh0,jh0) on even tile
    LDA_Q(A0b, 0); LDB_Q(B0b, b0, 0);
    STAGE_A(o, 1);
    BAR; PRIO1; MFMA_Q(0, 0, b0); PRIO0; BAR;
    // p1 (0,1)
    LDB_Q(B0b, b1, 1);
    STAGE_B(o, 0);
    BAR; PRIO1; MFMA_Q(0, 1, b1); PRIO0; BAR;
    // p2 (1,1)
    LDA_Q(A0b, 1);
    if (it < 3) STAGE_A(e + 2, 0);
    BAR; PRIO1; MFMA_Q(1, 1, b1); PRIO0; BAR;
    // p3 (1,0)  — gate: dbuf1 regions (staged through p1) must land
    if (it < 3) STAGE_B(e + 2, 1);
    BAR; PRIO1; MFMA_Q(1, 0, b0); PRIO0;
    if (it < 3) { GATE4; } else { GATE0; }
    // p4 (0,0) on odd tile
    LDA_Q(A1b, 0); LDB_Q(B1b, b0, 0);
    if (it < 3) STAGE_A(e + 2, 1);
    BAR; PRIO1; MFMA_Q(0, 0, b0); PRIO0; BAR;
    // p5 (0,1)
    LDB_Q(B1b, b1, 1);
    if (it < 3) STAGE_B(e + 2, 0);
    BAR; PRIO1; MFMA_Q(0, 1, b1); PRIO0; BAR;
    // p6 (1,1)
    LDA_Q(A1b, 1);
    if (it < 3) STAGE_A(o + 2, 0);
    BAR; PRIO1; MFMA_Q(1, 1, b1); PRIO0; BAR;
    // p7 (1,0)  — gate: next iteration's dbuf0 (staged p2..p5) must land
    if (it < 3) STAGE_B(o + 2, 1);
    BAR; PRIO1; MFMA_Q(1, 0, b0); PRIO0;
    if (it < 3) { GATE4; }
  }

  __syncthreads();   // full drain before epilogue LDS reuse

  // ---- epilogue: e = exp2(dot * 2*log2e); masked accumulate ----
  int labr[8][4];
#pragma unroll
  for (int m = 0; m < 8; ++m)
#pragma unroll
    for (int r = 0; r < 4; ++r)
      labr[m][r] = labels[rowbase + wr * 128 + m * 16 + lhi * 4 + r];
  int labc[4];
#pragma unroll
  for (int j = 0; j < 4; ++j) labc[j] = labels[colbase + wc * 64 + j * 16 + lr];

  float allrow[8][4] = {};
  float posrow[8][4] = {};
#pragma unroll
  for (int m = 0; m < 8; ++m)
#pragma unroll
    for (int j = 0; j < 4; ++j)
#pragma unroll
      for (int r = 0; r < 4; ++r) {
        float e = exp2f(acc[m][j][r] * INV_T_LOG2E);
        allrow[m][r] += e;
        if (labr[m][r] == labc[j]) posrow[m][r] += e;
      }

#pragma unroll
  for (int msk = 1; msk <= 8; msk <<= 1)
#pragma unroll
    for (int m = 0; m < 8; ++m)
#pragma unroll
      for (int r = 0; r < 4; ++r) {
        allrow[m][r] += __shfl_xor(allrow[m][r], msk);
        posrow[m][r] += __shfl_xor(posrow[m][r], msk);
      }

  // cross-wave reduce over wc; red buffers alias As (quiescent after sync).
  float* redA = (float*)&As[0][0];            // [3][2][128]
  float* redP = redA + 3 * 2 * 128;
  if (wc != 0 && lr == 0) {
#pragma unroll
    for (int m = 0; m < 8; ++m)
#pragma unroll
      for (int r = 0; r < 4; ++r) {
        int idx = m * 16 + lhi * 4 + r;
        redA[((wc - 1) * 2 + wr) * 128 + idx] = allrow[m][r];
        redP[((wc - 1) * 2 + wr) * 128 + idx] = posrow[m][r];
      }
  }
  __syncthreads();
  if (wc == 0 && lr == 0) {
#pragma unroll
    for (int m = 0; m < 8; ++m)
#pragma unroll
      for (int r = 0; r < 4; ++r) {
        int idx = m * 16 + lhi * 4 + r;
        float a = allrow[m][r], pp = posrow[m][r];
#pragma unroll
        for (int w = 0; w < 3; ++w) {
          a  += redA[(w * 2 + wr) * 128 + idx];
          pp += redP[(w * 2 + wr) * 128 + idx];
        }
        int row = rowbase + wr * 128 + idx;
        part_all[colgrp * N + row] = a;
        part_pos[colgrp * N + row] = pp;
      }
  }
}

// Stage 1: one row per thread, coalesced over cs; per-block tree reduce.
__global__ __launch_bounds__(256) void row_reduce(
    const float* __restrict__ part_pos, const float* __restrict__ part_all,
    float* __restrict__ blocksum) {
  const int i = blockIdx.x * 256 + threadIdx.x;
  float a = 0.f, p = 0.f;
#pragma unroll 4
  for (int cs = 0; cs < CGROUPS; ++cs) {
    a += part_all[(size_t)cs * N + i];
    p += part_pos[(size_t)cs * N + i];
  }
  float s = logf(a) - logf(p);
  __shared__ float red[256];
  red[threadIdx.x] = s;
  __syncthreads();
  for (int off = 128; off > 0; off >>= 1) {
    if (threadIdx.x < off) red[threadIdx.x] += red[threadIdx.x + off];
    __syncthreads();
  }
  if (threadIdx.x == 0) blocksum[blockIdx.x] = red[0];
}

__global__ __launch_bounds__(64) void final_sum(
    const float* __restrict__ blocksum, float* __restrict__ out) {
  float s = (threadIdx.x < N / 256) ? blocksum[threadIdx.x] : 0.f;
#pragma unroll
  for (int m = 1; m <= 32; m <<= 1) s += __shfl_xor(s, m);
  if (threadIdx.x == 0) out[0] = s / (float)N;
}

extern "C" void kernel_launch(void* const* d_in, const int* in_sizes, int n_in,
                              void* d_out, int out_size, void* d_ws, size_t ws_size,
                              hipStream_t stream) {
  const float* out0   = (const float*)d_in[0];
  const float* out1   = (const float*)d_in[1];
  const int*   labels = (const int*)d_in[2];
  float*       out    = (float*)d_out;

  char* ws = (char*)d_ws;
  unsigned short* n0 = (unsigned short*)ws;                          // 8 MB
  unsigned short* n1 = (unsigned short*)(ws + (size_t)N * D * 2);    // 8 MB
  float* part_pos = (float*)(ws + (size_t)2 * N * D * 2);            // 1 MB
  float* part_all = part_pos + (size_t)CGROUPS * N;                  // 1 MB
  float* blocksum = part_all + (size_t)CGROUPS * N;                  // 128 B

  hipLaunchKernelGGL(normalize_kernel, dim3(2 * N / 4), dim3(256), 0, stream,
                     out0, out1, n0, n1);
  hipLaunchKernelGGL(ntxent_main, dim3(32 * CGROUPS), dim3(512), 0, stream,
                     n0, n1, labels, part_pos, part_all);
  hipLaunchKernelGGL(row_reduce, dim3(N / 256), dim3(256), 0, stream,
                     part_pos, part_all, blocksum);
  hipLaunchKernelGGL(final_sum, dim3(1), dim3(64), 0, stream,
                     blocksum, out);
}